// Round 15
// baseline (24.042 us; speedup 1.0000x reference)
//
#include <hip/hip_runtime.h>

// Problem constants (fixed by the reference file): B=8, N=4096.
#define NN 4096
#define BB 8
#define JT 4   // ISNet rows (j) per block

typedef float v2f __attribute__((ext_vector_type(2)));

// R14 structure (best: 23.8 µs) + ONE change: a raw s_barrier per stage.
// Theory: the invariant ~24 µs wall is L2->L1 fill; 256 MB of it is the 4x
// w-redundancy (4 waves/block load the same 4 rows but drift out of L1's
// 32 KB window). Raw __builtin_amdgcn_s_barrier() (NO vmcnt drain -- unlike
// __syncthreads) keeps waves in ~1-stage lockstep so waves 2-4 hit L1 on w.
// Everything else identical to R14: packed-f32 factor math (v_pk_mul/fma),
// 8-factor f32 combine -> one f64 fma per 8 factors, w triple-buffered
// (dist 3), I double-buffered (dist 2), 3-xor + select + 3-down reduction.

__global__ __launch_bounds__(256, 4) void epi_kernel(
    const float* __restrict__ state,    // [B,4,N]
    const float* __restrict__ ISNet,    // [N,N]
    const float* __restrict__ psMatrix, // [4,4]
    const float* __restrict__ U,        // [N]
    float* __restrict__ out)            // [B,4,N]
{
    const int j0   = blockIdx.x * JT;
    const int tid  = threadIdx.x;
    const int wave = tid >> 6;
    const int lane = tid & 63;
    const int b0   = wave * 2;          // this wave's two batches

    const float p01 = psMatrix[1];      // psM[0,1] == psMatrix[0,1]

    float  cf[JT][2];
    float  qp[JT][2];                   // pending q4 from the even stage
    double prod[JT][2];
    #pragma unroll
    for (int jj = 0; jj < JT; ++jj) {
        #pragma unroll
        for (int bi = 0; bi < 2; ++bi) {
            cf[jj][bi]   = state[(size_t)(b0 + bi) * 4 * NN + (j0 + jj)] * p01;
            prod[jj][bi] = 1.0;
            qp[jj][bi]   = 0.0f;
        }
    }

    const float4* __restrict__ w0 = (const float4*)(ISNet + (size_t)(j0 + 0) * NN);
    const float4* __restrict__ w1 = (const float4*)(ISNet + (size_t)(j0 + 1) * NN);
    const float4* __restrict__ w2 = (const float4*)(ISNet + (size_t)(j0 + 2) * NN);
    const float4* __restrict__ w3 = (const float4*)(ISNet + (size_t)(j0 + 3) * NN);
    const float4* __restrict__ i0 = (const float4*)(state + ((size_t)(b0 + 0) * 4 + 2) * NN);
    const float4* __restrict__ i1 = (const float4*)(state + ((size_t)(b0 + 1) * 4 + 2) * NN);

    float4 wA[JT], wB[JT], wC[JT], ia[2], ib[2];

#define LW(BUF, IDX) do { const int _x = lane + (IDX) * 64; \
        BUF[0] = w0[_x]; BUF[1] = w1[_x]; BUF[2] = w2[_x]; BUF[3] = w3[_x]; } while (0)
#define LI(BUF, IDX) do { const int _x = lane + (IDX) * 64; \
        BUF[0] = i0[_x]; BUF[1] = i1[_x]; } while (0)

    auto compute = [&](const float4 (&W)[JT], const float4 (&I)[2], bool odd) {
        #pragma unroll
        for (int jj = 0; jj < JT; ++jj) {
            const v2f w01 = {W[jj].x, W[jj].y};
            const v2f w23 = {W[jj].z, W[jj].w};
            #pragma unroll
            for (int bi = 0; bi < 2; ++bi) {
                const float4& I4 = bi ? I[1] : I[0];
                const v2f c2  = {cf[jj][bi], cf[jj][bi]};
                const v2f i01 = {I4.x, I4.y};
                const v2f i23 = {I4.z, I4.w};
                const v2f z01 = (c2 * w01) * i01;              // v_pk_mul_f32
                const v2f z23 = (c2 * w23) * i23;              // v_pk_mul_f32
                const v2f q2  = __builtin_elementwise_fma(-z01, z23, z01 + z23);
                const float q4 = fmaf(-q2.x, q2.y, q2.x + q2.y);
                if (!odd) {
                    qp[jj][bi] = q4;                           // stash
                } else {
                    const float q8 = fmaf(-qp[jj][bi], q4, qp[jj][bi] + q4);
                    prod[jj][bi] = fma(-(double)q8, prod[jj][bi], prod[jj][bi]);
                }
            }
        }
    };

    // 16 stages; w triple-buffered (dist 3), I double-buffered (dist 2).
    // Raw s_barrier per stage keeps the block's 4 waves in L1-window lockstep.
#define STEP(W, I, K) do { compute(W, I, (K) & 1); \
        if ((K) + 3 < 16) LW(W, (K) + 3); if ((K) + 2 < 16) LI(I, (K) + 2); \
        if ((K) < 15) __builtin_amdgcn_s_barrier(); } while (0)

    LW(wA, 0); LI(ia, 0); LW(wB, 1); LI(ib, 1); LW(wC, 2);
    STEP(wA, ia, 0);  STEP(wB, ib, 1);  STEP(wC, ia, 2);  STEP(wA, ib, 3);
    STEP(wB, ia, 4);  STEP(wC, ib, 5);  STEP(wA, ia, 6);  STEP(wB, ib, 7);
    STEP(wC, ia, 8);  STEP(wA, ib, 9);  STEP(wB, ia, 10); STEP(wC, ib, 11);
    STEP(wA, ia, 12); STEP(wB, ib, 13); STEP(wC, ia, 14); STEP(wA, ib, 15);
#undef STEP
#undef LW
#undef LI

    // 3 XOR-butterfly levels -> every lane holds its mod-8 residue partial.
    #pragma unroll
    for (int off = 32; off >= 8; off >>= 1) {
        #pragma unroll
        for (int jj = 0; jj < JT; ++jj) {
            #pragma unroll
            for (int bi = 0; bi < 2; ++bi)
                prod[jj][bi] *= __shfl_xor(prod[jj][bi], off, 64);
        }
    }

    // 8-lane group g reduces pair g = (jj<<1)|bi.
    const int g = lane >> 3;
    double v = prod[0][0];
    v = (g == 1) ? prod[0][1] : v; v = (g == 2) ? prod[1][0] : v;
    v = (g == 3) ? prod[1][1] : v; v = (g == 4) ? prod[2][0] : v;
    v = (g == 5) ? prod[2][1] : v; v = (g == 6) ? prod[3][0] : v;
    v = (g == 7) ? prod[3][1] : v;
    v *= __shfl_down(v, 4, 64);
    v *= __shfl_down(v, 2, 64);
    v *= __shfl_down(v, 1, 64);

    __shared__ double red[JT][BB];
    if ((lane & 7) == 0)               // pair g = (jj<<1)|bi
        red[g >> 1][b0 + (g & 1)] = v;
    __syncthreads();

    if (tid < JT * BB) {   // 32 threads: (jj, b)
        const int jj = tid >> 3, b = tid & 7;
        const int j  = j0 + jj;
        const double ps1 = 1.0 - red[jj][b];

        // expand_psMatrix in f64
        double pm[4][4];
        #pragma unroll
        for (int r = 0; r < 4; ++r) {
            double s = 0.0;
            #pragma unroll
            for (int q = 0; q < 4; ++q) {
                pm[r][q] = (double)psMatrix[r * 4 + q];
                s += pm[r][q];
            }
            pm[r][r] += (1.0 - s);
        }

        double st[4];
        #pragma unroll
        for (int r = 0; r < 4; ++r)
            st[r] = (double)state[(size_t)b * 4 * NN + r * NN + j];

        const double S = st[0];
        const double ps10[4] = {1.0 - ps1, ps1, 0.0, 0.0};

        double P[4];
        #pragma unroll
        for (int i = 0; i < 4; ++i) {
            double acc = S * ps10[i];
            #pragma unroll
            for (int r = 1; r < 4; ++r)
                acc += pm[r][i] * st[r];
            P[i] = acc;
        }

        double u = (double)U[j];
        #pragma unroll
        for (int i = 0; i < 4; ++i) {
            u -= P[i];
            const double s = (u < 0.0) ? 1.0 : 0.0;
            out[(size_t)b * 4 * NN + i * NN + j] = (float)s;
            u += s;
        }
    }
}

extern "C" void kernel_launch(void* const* d_in, const int* in_sizes, int n_in,
                              void* d_out, int out_size, void* d_ws, size_t ws_size,
                              hipStream_t stream) {
    const float* state    = (const float*)d_in[0];  // [8,4,4096]
    const float* ISNet    = (const float*)d_in[1];  // [4096,4096]
    const float* psMatrix = (const float*)d_in[2];  // [4,4]
    const float* U        = (const float*)d_in[3];  // [4096]
    float* out            = (float*)d_out;          // [8,4,4096]

    epi_kernel<<<NN / JT, 256, 0, stream>>>(state, ISNet, psMatrix, U, out);
}